// Round 5
// baseline (158.620 us; speedup 1.0000x reference)
//
#include <hip/hip_runtime.h>
#include <math.h>

#define D 128
#define GRAPHS 64

typedef __attribute__((ext_vector_type(8))) short bf16x8;
typedef __attribute__((ext_vector_type(4))) float f32x4;

union U4H8 { uint4 u; bf16x8 h; };

__device__ __forceinline__ unsigned short f2bf(float f) {   // RNE
  union { float f; unsigned u; } v; v.f = f;
  unsigned r = v.u + 0x7fffu + ((v.u >> 16) & 1u);
  return (unsigned short)(r >> 16);
}
__device__ __forceinline__ unsigned asu(float f) {
  union { float f; unsigned u; } v; v.f = f; return v.u;
}
__device__ __forceinline__ float asf(unsigned u) {
  union { unsigned u; float f; } v; v.u = u; return v.f;
}

// ---------------------------------------------------------------------------
// Gram partials: grid = GRAPHS*KS blocks x 256 thr (4 waves). Block (g,sl):
// fp32-register XsT*Xs over chunk=L/KS rows (acc[2][8], 64 VGPR), K-chunks of
// 64 rows (32 KB/block in flight -> BW-saturated; feats read EXACTLY once
// chip-wide). bf16 partial written coalesced via LDS round-trip.
// ---------------------------------------------------------------------------
__global__ __launch_bounds__(256, 2) void gram_partial_kernel(
    const float* __restrict__ feats, unsigned short* __restrict__ partial,
    int L, int KS) {
  const int g = blockIdx.x / KS;
  const int sl = blockIdx.x - g * KS;
  const int chunk = L / KS;
  const float* __restrict__ X = feats + ((size_t)g * L + (size_t)sl * chunk) * D;

  __shared__ __align__(16) unsigned short smem[16384];  // 32 KB (stage uses 16)
  const int tid = threadIdx.x;
  const int wv = tid >> 6, lane = tid & 63, quad = lane >> 4, ln = lane & 15;

  f32x4 acc[2][8];
#pragma unroll
  for (int rt = 0; rt < 2; ++rt)
#pragma unroll
    for (int ct = 0; ct < 8; ++ct) acc[rt][ct] = (f32x4)(0.f);

  // 1024 pair-tasks (32 k-pairs x 32 d4) per 64-row chunk, 4 per thread
  int k2v[4], d4v[4];
#pragma unroll
  for (int v = 0; v < 4; ++v) {
    int tt = tid + v * 256;
    k2v[v] = tt & 31;
    d4v[v] = tt >> 5;
  }
  float4 pf[8];
#pragma unroll
  for (int v = 0; v < 4; ++v) {
    pf[2 * v] = *(const float4*)(X + (size_t)(2 * k2v[v]) * D + 4 * d4v[v]);
    pf[2 * v + 1] = *(const float4*)(X + (size_t)(2 * k2v[v] + 1) * D + 4 * d4v[v]);
  }

  for (int it = 0; it < chunk; it += 64) {
    __syncthreads();
#pragma unroll
    for (int v = 0; v < 4; ++v) {
      const float* p0 = (const float*)&pf[2 * v];
      const float* p1 = (const float*)&pf[2 * v + 1];
      int k = 2 * k2v[v];
      int ks = k >> 5, kk = k & 31, qs = kk >> 3, j = kk & 7;
#pragma unroll
      for (int i = 0; i < 4; ++i) {
        int d = 4 * d4v[v] + i, t = d >> 4, lnw = d & 15;
        *(unsigned*)&smem[((ks * 8 + t) * 64 + qs * 16 + lnw) * 8 + j] =
            (unsigned)f2bf(p0[i]) | ((unsigned)f2bf(p1[i]) << 16);
      }
    }
    __syncthreads();
    if (it + 64 < chunk) {  // prefetch next 64-row chunk
      const float* Xn = X + (size_t)(it + 64) * D;
#pragma unroll
      for (int v = 0; v < 4; ++v) {
        pf[2 * v] = *(const float4*)(Xn + (size_t)(2 * k2v[v]) * D + 4 * d4v[v]);
        pf[2 * v + 1] =
            *(const float4*)(Xn + (size_t)(2 * k2v[v] + 1) * D + 4 * d4v[v]);
      }
    }
#pragma unroll
    for (int ks = 0; ks < 2; ++ks) {
      bf16x8 af[2], bfr[8];
      af[0] = *(const bf16x8*)&smem[((ks * 8 + 2 * wv) * 64 + lane) * 8];
      af[1] = *(const bf16x8*)&smem[((ks * 8 + 2 * wv + 1) * 64 + lane) * 8];
#pragma unroll
      for (int ct = 0; ct < 8; ++ct)
        bfr[ct] = *(const bf16x8*)&smem[((ks * 8 + ct) * 64 + lane) * 8];
#pragma unroll
      for (int rt = 0; rt < 2; ++rt)
#pragma unroll
        for (int ct = 0; ct < 8; ++ct)
          acc[rt][ct] = __builtin_amdgcn_mfma_f32_16x16x32_bf16(
              af[rt], bfr[ct], acc[rt][ct], 0, 0, 0);
    }
  }

  // park C-layout -> row-major bf16 in LDS, then coalesced writeout
  __syncthreads();
#pragma unroll
  for (int rt = 0; rt < 2; ++rt)
#pragma unroll
    for (int ct = 0; ct < 8; ++ct)
#pragma unroll
      for (int r = 0; r < 4; ++r)
        smem[(32 * wv + 16 * rt + quad * 4 + r) * 128 + 16 * ct + ln] =
            f2bf(acc[rt][ct][r]);
  __syncthreads();
  unsigned short* P = partial + ((size_t)sl * GRAPHS + g) * (D * D);
#pragma unroll
  for (int v = 0; v < 8; ++v) {
    int idx = tid + v * 256;
    *(uint4*)&P[(size_t)idx * 8] = *(uint4*)&smem[idx * 8];
  }
}

// ---------------------------------------------------------------------------
// Reduce KS bf16 partials -> bf16 gram (blocks 0..511) + w2 (blocks 512..519).
// ---------------------------------------------------------------------------
__global__ __launch_bounds__(256) void reduce_w2_kernel(
    const unsigned short* __restrict__ partial, unsigned short* __restrict__ gram,
    const float* __restrict__ w, unsigned short* __restrict__ w2, int KS) {
  const int bid = blockIdx.x;
  if (bid < 512) {
    int idx = bid * 256 + threadIdx.x;  // each handles 8 elems
    int e8 = idx * 8;
    int g = e8 >> 14, e = e8 & (D * D - 1);
    float s[8];
#pragma unroll
    for (int i = 0; i < 8; ++i) s[i] = 0.f;
    for (int sl = 0; sl < KS; ++sl) {
      uint4 t = *(const uint4*)&partial[((size_t)sl * GRAPHS + g) * (D * D) + e];
      const unsigned* tp = &t.x;
#pragma unroll
      for (int q = 0; q < 4; ++q) {
        s[2 * q] += asf(tp[q] << 16);
        s[2 * q + 1] += asf(tp[q] & 0xFFFF0000u);
      }
    }
    uint4 o;
    o.x = (unsigned)f2bf(s[0]) | ((unsigned)f2bf(s[1]) << 16);
    o.y = (unsigned)f2bf(s[2]) | ((unsigned)f2bf(s[3]) << 16);
    o.z = (unsigned)f2bf(s[4]) | ((unsigned)f2bf(s[5]) << 16);
    o.w = (unsigned)f2bf(s[6]) | ((unsigned)f2bf(s[7]) << 16);
    *(uint4*)&gram[(size_t)g * (D * D) + e] = o;
  } else {
    int idx = (bid - 512) * 256 + threadIdx.x;  // 2048 thr x 8 elems
    const float* src = w + (size_t)idx * 8;
    float4 a = *(const float4*)src;
    float4 b = *(const float4*)(src + 4);
    uint4 o;
    o.x = (unsigned)f2bf(a.x * a.x) | ((unsigned)f2bf(a.y * a.y) << 16);
    o.y = (unsigned)f2bf(a.z * a.z) | ((unsigned)f2bf(a.w * a.w) << 16);
    o.z = (unsigned)f2bf(b.x * b.x) | ((unsigned)f2bf(b.y * b.y) << 16);
    o.w = (unsigned)f2bf(b.z * b.z) | ((unsigned)f2bf(b.w * b.w) << 16);
    *(uint4*)&w2[(size_t)idx * 8] = o;
  }
}

// ---------------------------------------------------------------------------
// Fused main. grid = GRAPHS*(L/64) = 2048 blocks x 512 thr (8 waves).
// Block = 64 rows; wave (rowg=wv>>1, colg=wv&1) = 16 rows x 64 cols.
// Phase-2 accs = 48 VGPR -> fits 128-VGPR cap (launch_bounds(512,4)):
// 4 waves/SIMD, 2 blocks/CU. Repack redundancy 2x (occupancy > dedup, per R5).
// ---------------------------------------------------------------------------
__global__ __launch_bounds__(512, 4) void fused_kernel4(
    const float* __restrict__ feats, const unsigned short* __restrict__ gram,
    const unsigned short* __restrict__ w2, float* __restrict__ out, int L) {
  const int tiles = L >> 6;
  const int gi = blockIdx.x / tiles;
  const int row0 = (blockIdx.x - gi * tiles) << 6;
  const float* __restrict__ A = feats + ((size_t)gi * L + row0) * D;
  const unsigned short* __restrict__ G = gram + (size_t)(gi ^ 1) * (D * D);
  float* __restrict__ O = out + ((size_t)gi * L + row0) * D;

  __shared__ __align__(16) unsigned short sAf[8192];   // ((kc*4+rt)*64+lane)*8
  __shared__ __align__(16) unsigned short sVf[8192];
  __shared__ __align__(16) unsigned short sBf[16384];  // ((kc*8+tb)*64+lane)*8

  const int tid = threadIdx.x;
  const int wv = tid >> 6, lane = tid & 63, quad = lane >> 4, ln = lane & 15;
  const int rowg = wv >> 1, colg = wv & 1;

  // stage A (fp32 -> bf16, frag order): 2048 float4 tasks, 4/thread
#pragma unroll
  for (int v = 0; v < 4; ++v) {
    int idx = tid + v * 512;
    int r = idx >> 5, c4 = idx & 31;
    float4 t = *(const float4*)(A + (size_t)r * D + c4 * 4);
    int kc = c4 >> 3, qd = (c4 & 7) >> 1, j0 = (c4 & 1) * 4;
    int rt = r >> 4, lnw = r & 15;
    uint2 pk;
    pk.x = (unsigned)f2bf(t.x) | ((unsigned)f2bf(t.y) << 16);
    pk.y = (unsigned)f2bf(t.z) | ((unsigned)f2bf(t.w) << 16);
    *(uint2*)&sAf[((kc * 4 + rt) * 64 + qd * 16 + lnw) * 8 + j0] = pk;
  }
  // stage Gram (bf16 frag order): 2048 uint4 tasks, 4/thread
#pragma unroll
  for (int v = 0; v < 4; ++v) {
    int idx = tid + v * 512;
    int r = idx >> 4, c16 = idx & 15;
    uint4 t = *(const uint4*)(G + (size_t)r * D + c16 * 8);
    int kc = c16 >> 2, qd = c16 & 3, tb = r >> 4, lnw = r & 15;
    *(uint4*)&sBf[((kc * 8 + tb) * 64 + qd * 16 + lnw) * 8] = t;
  }
  __syncthreads();

  // ---- phase 1: V2 = A * Gram (wave: 16 rows x 64 cols) ----
  f32x4 acc1[4];
#pragma unroll
  for (int c = 0; c < 4; ++c) acc1[c] = (f32x4)(0.f);
#pragma unroll
  for (int kc = 0; kc < 4; ++kc) {
    bf16x8 af = *(const bf16x8*)&sAf[((kc * 4 + rowg) * 64 + lane) * 8];
#pragma unroll
    for (int c = 0; c < 4; ++c) {
      int ct = colg * 4 + c;
      bf16x8 bfr = *(const bf16x8*)&sBf[((kc * 8 + ct) * 64 + lane) * 8];
      acc1[c] = __builtin_amdgcn_mfma_f32_16x16x32_bf16(af, bfr, acc1[c], 0, 0, 0);
    }
  }
  // park V2 (C-layout -> A-frag order)
#pragma unroll
  for (int c = 0; c < 4; ++c)
#pragma unroll
    for (int r = 0; r < 4; ++r) {
      int col = (colg * 4 + c) * 16 + ln;
      int kc_t = col >> 5, q_t = (col >> 3) & 3, j_t = col & 7;
      sVf[((kc_t * 4 + rowg) * 64 + q_t * 16 + quad * 4 + r) * 8 + j_t] =
          f2bf(acc1[c][r]);
    }
  __syncthreads();

  // stage W2 into sBf (frag order)
#pragma unroll
  for (int v = 0; v < 4; ++v) {
    int idx = tid + v * 512;
    int r = idx >> 4, c16 = idx & 15;
    uint4 t = *(const uint4*)(w2 + (size_t)r * D + c16 * 8);
    int kc = c16 >> 2, qd = c16 & 3, tb = r >> 4, lnw = r & 15;
    *(uint4*)&sBf[((kc * 8 + tb) * 64 + qd * 16 + lnw) * 8] = t;
  }
  __syncthreads();

  // ---- phase 2: three GEMMs vs W2 ----
  f32x4 an[4], s1[4], s2[4];
#pragma unroll
  for (int c = 0; c < 4; ++c) {
    an[c] = (f32x4)(0.f);
    s1[c] = (f32x4)(0.f);
    s2[c] = (f32x4)(0.f);
  }
#pragma unroll
  for (int dc = 0; dc < 4; ++dc) {
    uint4 ua = *(const uint4*)&sAf[((dc * 4 + rowg) * 64 + lane) * 8];
    uint4 uv = *(const uint4*)&sVf[((dc * 4 + rowg) * 64 + lane) * 8];
    U4H8 fx2, faa, fvv;
    const unsigned* uap = &ua.x;
    const unsigned* uvp = &uv.x;
#pragma unroll
    for (int q = 0; q < 4; ++q) {
      float a0 = asf(uap[q] << 16), a1 = asf(uap[q] & 0xFFFF0000u);
      float v0 = asf(uvp[q] << 16), v1 = asf(uvp[q] & 0xFFFF0000u);
      (&fx2.u.x)[q] = __builtin_amdgcn_perm(asu(a1 * v1), asu(a0 * v0), 0x07060302u);
      (&faa.u.x)[q] = __builtin_amdgcn_perm(asu(a1 * a1), asu(a0 * a0), 0x07060302u);
      (&fvv.u.x)[q] = __builtin_amdgcn_perm(asu(v1 * v1), asu(v0 * v0), 0x07060302u);
    }
#pragma unroll
    for (int c = 0; c < 4; ++c) {
      int ct = colg * 4 + c;
      bf16x8 wf = *(const bf16x8*)&sBf[((dc * 8 + ct) * 64 + lane) * 8];
      an[c] = __builtin_amdgcn_mfma_f32_16x16x32_bf16(fx2.h, wf, an[c], 0, 0, 0);
      s1[c] = __builtin_amdgcn_mfma_f32_16x16x32_bf16(faa.h, wf, s1[c], 0, 0, 0);
      s2[c] = __builtin_amdgcn_mfma_f32_16x16x32_bf16(fvv.h, wf, s2[c], 0, 0, 0);
    }
  }

  // ---- epilogue ----
#pragma unroll
  for (int c = 0; c < 4; ++c)
#pragma unroll
    for (int r = 0; r < 4; ++r) {
      float t = fmaxf(s1[c][r] * s2[c][r], 1e-16f);
      O[(size_t)(rowg * 16 + quad * 4 + r) * D + (colg * 4 + c) * 16 + ln] =
          an[c][r] * __builtin_amdgcn_rsqf(t);
    }
}

extern "C" void kernel_launch(void* const* d_in, const int* in_sizes, int n_in,
                              void* d_out, int out_size, void* d_ws, size_t ws_size,
                              hipStream_t stream) {
  const float* feats = (const float*)d_in[0];
  const float* w = (const float*)d_in[1];
  float* out = (float*)d_out;
  const int L = (in_sizes[0] / D) / GRAPHS;  // 2048

  const size_t partSlice = (size_t)GRAPHS * D * D * sizeof(unsigned short);  // 2 MiB
  const size_t gramB = partSlice;                                            // 2 MiB
  const size_t w2B = (size_t)D * D * sizeof(unsigned short);                 // 32 KiB
  int KS = 4;
  while (KS > 1 && (size_t)KS * partSlice + gramB + w2B > ws_size) KS >>= 1;

  unsigned short* partialBuf = (unsigned short*)d_ws;
  unsigned short* gramBuf = partialBuf + (size_t)KS * GRAPHS * D * D;
  unsigned short* w2Buf = gramBuf + (size_t)GRAPHS * D * D;

  hipLaunchKernelGGL(gram_partial_kernel, dim3(GRAPHS * KS), dim3(256), 0,
                     stream, feats, partialBuf, L, KS);
  hipLaunchKernelGGL(reduce_w2_kernel, dim3(520), dim3(256), 0, stream,
                     partialBuf, gramBuf, w, w2Buf, KS);
  hipLaunchKernelGGL(fused_kernel4, dim3(GRAPHS * (L >> 6)), dim3(512), 0,
                     stream, feats, gramBuf, w2Buf, out, L);
}

// Round 8
// 156.197 us; speedup vs baseline: 1.0155x; 1.0155x over previous
//
#include <hip/hip_runtime.h>
#include <math.h>

#define D 128
#define GRAPHS 64

typedef __attribute__((ext_vector_type(8))) short bf16x8;
typedef __attribute__((ext_vector_type(4))) float f32x4;

union U4H8 { uint4 u; bf16x8 h; };

__device__ __forceinline__ unsigned short f2bf(float f) {   // RNE
  union { float f; unsigned u; } v; v.f = f;
  unsigned r = v.u + 0x7fffu + ((v.u >> 16) & 1u);
  return (unsigned short)(r >> 16);
}
__device__ __forceinline__ unsigned asu(float f) {
  union { float f; unsigned u; } v; v.f = f; return v.u;
}
__device__ __forceinline__ float asf(unsigned u) {
  union { unsigned u; float f; } v; v.u = u; return v.f;
}

// 16B-unit bank swizzles (bijective involutions: XOR source bits disjoint from
// modified bits 1-2). swzA for 1024-unit buffers (sAf/sVf), swzB for 2048-unit
// buffers (sBf). Spreads the staging/park writes (which pin U%8 constant
// across a 16-lane group -> 8-16-way conflict) across 4 bank groups while
// leaving the b128 fragment reads' pattern intact (the XOR permutes lanes
// within 8-lane groups; per-quarter-wave address sets unchanged).
__device__ __forceinline__ int swzA(int u) {
  return u ^ (((((u >> 8) ^ (u >> 4)) & 3) ^ ((u >> 3) & 1)) << 1);
}
__device__ __forceinline__ int swzB(int u) {
  return u ^ ((((u >> 9) ^ (u >> 4)) & 3) << 1);
}

// ---------------------------------------------------------------------------
// Gram partials: grid = GRAPHS*KS blocks x 256 thr (4 waves). Block (g,sl):
// fp32-register XsT*Xs over chunk=L/KS rows (acc[2][8], 64 VGPR), K-chunks of
// 64 rows. KS=16 -> 1024 blocks (vs 256 at KS=4): 1 wave/SIMD was 3% occupancy
// with full HBM-latency exposure per barrier-fenced chunk; 4x blocks gives
// 2+ blocks/CU and 4x shorter per-block dependent chain. bf16 partial written
// coalesced via LDS round-trip.
// ---------------------------------------------------------------------------
__global__ __launch_bounds__(256, 2) void gram_partial_kernel(
    const float* __restrict__ feats, unsigned short* __restrict__ partial,
    int L, int KS) {
  const int g = blockIdx.x / KS;
  const int sl = blockIdx.x - g * KS;
  const int chunk = L / KS;
  const float* __restrict__ X = feats + ((size_t)g * L + (size_t)sl * chunk) * D;

  __shared__ __align__(16) unsigned short smem[16384];  // 32 KB (stage uses 16)
  const int tid = threadIdx.x;
  const int wv = tid >> 6, lane = tid & 63, quad = lane >> 4, ln = lane & 15;

  f32x4 acc[2][8];
#pragma unroll
  for (int rt = 0; rt < 2; ++rt)
#pragma unroll
    for (int ct = 0; ct < 8; ++ct) acc[rt][ct] = (f32x4)(0.f);

  // 1024 pair-tasks (32 k-pairs x 32 d4) per 64-row chunk, 4 per thread
  int k2v[4], d4v[4];
#pragma unroll
  for (int v = 0; v < 4; ++v) {
    int tt = tid + v * 256;
    k2v[v] = tt & 31;
    d4v[v] = tt >> 5;
  }
  float4 pf[8];
#pragma unroll
  for (int v = 0; v < 4; ++v) {
    pf[2 * v] = *(const float4*)(X + (size_t)(2 * k2v[v]) * D + 4 * d4v[v]);
    pf[2 * v + 1] = *(const float4*)(X + (size_t)(2 * k2v[v] + 1) * D + 4 * d4v[v]);
  }

  for (int it = 0; it < chunk; it += 64) {
    __syncthreads();
#pragma unroll
    for (int v = 0; v < 4; ++v) {
      const float* p0 = (const float*)&pf[2 * v];
      const float* p1 = (const float*)&pf[2 * v + 1];
      int k = 2 * k2v[v];
      int ks = k >> 5, kk = k & 31, qs = kk >> 3, j = kk & 7;
#pragma unroll
      for (int i = 0; i < 4; ++i) {
        int d = 4 * d4v[v] + i, t = d >> 4, lnw = d & 15;
        *(unsigned*)&smem[((ks * 8 + t) * 64 + qs * 16 + lnw) * 8 + j] =
            (unsigned)f2bf(p0[i]) | ((unsigned)f2bf(p1[i]) << 16);
      }
    }
    __syncthreads();
    if (it + 64 < chunk) {  // prefetch next 64-row chunk
      const float* Xn = X + (size_t)(it + 64) * D;
#pragma unroll
      for (int v = 0; v < 4; ++v) {
        pf[2 * v] = *(const float4*)(Xn + (size_t)(2 * k2v[v]) * D + 4 * d4v[v]);
        pf[2 * v + 1] =
            *(const float4*)(Xn + (size_t)(2 * k2v[v] + 1) * D + 4 * d4v[v]);
      }
    }
#pragma unroll
    for (int ks = 0; ks < 2; ++ks) {
      bf16x8 af[2], bfr[8];
      af[0] = *(const bf16x8*)&smem[((ks * 8 + 2 * wv) * 64 + lane) * 8];
      af[1] = *(const bf16x8*)&smem[((ks * 8 + 2 * wv + 1) * 64 + lane) * 8];
#pragma unroll
      for (int ct = 0; ct < 8; ++ct)
        bfr[ct] = *(const bf16x8*)&smem[((ks * 8 + ct) * 64 + lane) * 8];
#pragma unroll
      for (int rt = 0; rt < 2; ++rt)
#pragma unroll
        for (int ct = 0; ct < 8; ++ct)
          acc[rt][ct] = __builtin_amdgcn_mfma_f32_16x16x32_bf16(
              af[rt], bfr[ct], acc[rt][ct], 0, 0, 0);
    }
  }

  // park C-layout -> row-major bf16 in LDS, then coalesced writeout
  __syncthreads();
#pragma unroll
  for (int rt = 0; rt < 2; ++rt)
#pragma unroll
    for (int ct = 0; ct < 8; ++ct)
#pragma unroll
      for (int r = 0; r < 4; ++r)
        smem[(32 * wv + 16 * rt + quad * 4 + r) * 128 + 16 * ct + ln] =
            f2bf(acc[rt][ct][r]);
  __syncthreads();
  unsigned short* P = partial + ((size_t)sl * GRAPHS + g) * (D * D);
#pragma unroll
  for (int v = 0; v < 8; ++v) {
    int idx = tid + v * 256;
    *(uint4*)&P[(size_t)idx * 8] = *(uint4*)&smem[idx * 8];
  }
}

// ---------------------------------------------------------------------------
// Reduce KS bf16 partials -> bf16 gram (blocks 0..511) + w2 (blocks 512..519).
// ---------------------------------------------------------------------------
__global__ __launch_bounds__(256) void reduce_w2_kernel(
    const unsigned short* __restrict__ partial, unsigned short* __restrict__ gram,
    const float* __restrict__ w, unsigned short* __restrict__ w2, int KS) {
  const int bid = blockIdx.x;
  if (bid < 512) {
    int idx = bid * 256 + threadIdx.x;  // each handles 8 elems
    int e8 = idx * 8;
    int g = e8 >> 14, e = e8 & (D * D - 1);
    float s[8];
#pragma unroll
    for (int i = 0; i < 8; ++i) s[i] = 0.f;
    for (int sl = 0; sl < KS; ++sl) {
      uint4 t = *(const uint4*)&partial[((size_t)sl * GRAPHS + g) * (D * D) + e];
      const unsigned* tp = &t.x;
#pragma unroll
      for (int q = 0; q < 4; ++q) {
        s[2 * q] += asf(tp[q] << 16);
        s[2 * q + 1] += asf(tp[q] & 0xFFFF0000u);
      }
    }
    uint4 o;
    o.x = (unsigned)f2bf(s[0]) | ((unsigned)f2bf(s[1]) << 16);
    o.y = (unsigned)f2bf(s[2]) | ((unsigned)f2bf(s[3]) << 16);
    o.z = (unsigned)f2bf(s[4]) | ((unsigned)f2bf(s[5]) << 16);
    o.w = (unsigned)f2bf(s[6]) | ((unsigned)f2bf(s[7]) << 16);
    *(uint4*)&gram[(size_t)g * (D * D) + e] = o;
  } else {
    int idx = (bid - 512) * 256 + threadIdx.x;  // 2048 thr x 8 elems
    const float* src = w + (size_t)idx * 8;
    float4 a = *(const float4*)src;
    float4 b = *(const float4*)(src + 4);
    uint4 o;
    o.x = (unsigned)f2bf(a.x * a.x) | ((unsigned)f2bf(a.y * a.y) << 16);
    o.y = (unsigned)f2bf(a.z * a.z) | ((unsigned)f2bf(a.w * a.w) << 16);
    o.z = (unsigned)f2bf(b.x * b.x) | ((unsigned)f2bf(b.y * b.y) << 16);
    o.w = (unsigned)f2bf(b.z * b.z) | ((unsigned)f2bf(b.w * b.w) << 16);
    *(uint4*)&w2[(size_t)idx * 8] = o;
  }
}

// ---------------------------------------------------------------------------
// Fused main. grid = GRAPHS*(L/64) = 2048 blocks x 512 thr (8 waves).
// Block = 64 rows; wave (rowg=wv>>1, colg=wv&1) = 16 rows x 64 cols.
// R5 profile: latency-bound (MfmaUtil 15%, VALUBusy 31%, occ 32%) with 9.7M
// LDS bank-conflict cycles (~16us/CU of LDS-pipe serialization). All sAf/sVf/
// sBf accesses now go through swzA/swzB 16B-unit swizzles: staging writes had
// U%8 constant per 16-lane group (16-way on sBf, 8-way on sAf, 4-8 on park).
// ---------------------------------------------------------------------------
__global__ __launch_bounds__(512, 4) void fused_kernel4(
    const float* __restrict__ feats, const unsigned short* __restrict__ gram,
    const unsigned short* __restrict__ w2, float* __restrict__ out, int L) {
  const int tiles = L >> 6;
  const int gi = blockIdx.x / tiles;
  const int row0 = (blockIdx.x - gi * tiles) << 6;
  const float* __restrict__ A = feats + ((size_t)gi * L + row0) * D;
  const unsigned short* __restrict__ G = gram + (size_t)(gi ^ 1) * (D * D);
  float* __restrict__ O = out + ((size_t)gi * L + row0) * D;

  __shared__ __align__(16) unsigned short sAf[8192];   // swzA(((kc*4+rt)*64+lane))*8
  __shared__ __align__(16) unsigned short sVf[8192];
  __shared__ __align__(16) unsigned short sBf[16384];  // swzB(((kc*8+tb)*64+lane))*8

  const int tid = threadIdx.x;
  const int wv = tid >> 6, lane = tid & 63, quad = lane >> 4, ln = lane & 15;
  const int rowg = wv >> 1, colg = wv & 1;

  // stage A (fp32 -> bf16, frag order): 2048 float4 tasks, 4/thread
#pragma unroll
  for (int v = 0; v < 4; ++v) {
    int idx = tid + v * 512;
    int r = idx >> 5, c4 = idx & 31;
    float4 t = *(const float4*)(A + (size_t)r * D + c4 * 4);
    int kc = c4 >> 3, qd = (c4 & 7) >> 1, j0 = (c4 & 1) * 4;
    int rt = r >> 4, lnw = r & 15;
    uint2 pk;
    pk.x = (unsigned)f2bf(t.x) | ((unsigned)f2bf(t.y) << 16);
    pk.y = (unsigned)f2bf(t.z) | ((unsigned)f2bf(t.w) << 16);
    *(uint2*)&sAf[swzA((kc * 4 + rt) * 64 + qd * 16 + lnw) * 8 + j0] = pk;
  }
  // stage Gram (bf16 frag order): 2048 uint4 tasks, 4/thread
#pragma unroll
  for (int v = 0; v < 4; ++v) {
    int idx = tid + v * 512;
    int r = idx >> 4, c16 = idx & 15;
    uint4 t = *(const uint4*)(G + (size_t)r * D + c16 * 8);
    int kc = c16 >> 2, qd = c16 & 3, tb = r >> 4, lnw = r & 15;
    *(uint4*)&sBf[swzB((kc * 8 + tb) * 64 + qd * 16 + lnw) * 8] = t;
  }
  __syncthreads();

  // ---- phase 1: V2 = A * Gram (wave: 16 rows x 64 cols) ----
  f32x4 acc1[4];
#pragma unroll
  for (int c = 0; c < 4; ++c) acc1[c] = (f32x4)(0.f);
#pragma unroll
  for (int kc = 0; kc < 4; ++kc) {
    bf16x8 af = *(const bf16x8*)&sAf[swzA((kc * 4 + rowg) * 64 + lane) * 8];
#pragma unroll
    for (int c = 0; c < 4; ++c) {
      int ct = colg * 4 + c;
      bf16x8 bfr = *(const bf16x8*)&sBf[swzB((kc * 8 + ct) * 64 + lane) * 8];
      acc1[c] = __builtin_amdgcn_mfma_f32_16x16x32_bf16(af, bfr, acc1[c], 0, 0, 0);
    }
  }
  // park V2 (C-layout -> A-frag order)
#pragma unroll
  for (int c = 0; c < 4; ++c)
#pragma unroll
    for (int r = 0; r < 4; ++r) {
      int col = (colg * 4 + c) * 16 + ln;
      int kc_t = col >> 5, q_t = (col >> 3) & 3, j_t = col & 7;
      sVf[swzA((kc_t * 4 + rowg) * 64 + q_t * 16 + quad * 4 + r) * 8 + j_t] =
          f2bf(acc1[c][r]);
    }
  __syncthreads();

  // stage W2 into sBf (frag order)
#pragma unroll
  for (int v = 0; v < 4; ++v) {
    int idx = tid + v * 512;
    int r = idx >> 4, c16 = idx & 15;
    uint4 t = *(const uint4*)(w2 + (size_t)r * D + c16 * 8);
    int kc = c16 >> 2, qd = c16 & 3, tb = r >> 4, lnw = r & 15;
    *(uint4*)&sBf[swzB((kc * 8 + tb) * 64 + qd * 16 + lnw) * 8] = t;
  }
  __syncthreads();

  // ---- phase 2: three GEMMs vs W2 ----
  f32x4 an[4], s1[4], s2[4];
#pragma unroll
  for (int c = 0; c < 4; ++c) {
    an[c] = (f32x4)(0.f);
    s1[c] = (f32x4)(0.f);
    s2[c] = (f32x4)(0.f);
  }
#pragma unroll
  for (int dc = 0; dc < 4; ++dc) {
    uint4 ua = *(const uint4*)&sAf[swzA((dc * 4 + rowg) * 64 + lane) * 8];
    uint4 uv = *(const uint4*)&sVf[swzA((dc * 4 + rowg) * 64 + lane) * 8];
    U4H8 fx2, faa, fvv;
    const unsigned* uap = &ua.x;
    const unsigned* uvp = &uv.x;
#pragma unroll
    for (int q = 0; q < 4; ++q) {
      float a0 = asf(uap[q] << 16), a1 = asf(uap[q] & 0xFFFF0000u);
      float v0 = asf(uvp[q] << 16), v1 = asf(uvp[q] & 0xFFFF0000u);
      (&fx2.u.x)[q] = __builtin_amdgcn_perm(asu(a1 * v1), asu(a0 * v0), 0x07060302u);
      (&faa.u.x)[q] = __builtin_amdgcn_perm(asu(a1 * a1), asu(a0 * a0), 0x07060302u);
      (&fvv.u.x)[q] = __builtin_amdgcn_perm(asu(v1 * v1), asu(v0 * v0), 0x07060302u);
    }
#pragma unroll
    for (int c = 0; c < 4; ++c) {
      int ct = colg * 4 + c;
      bf16x8 wf = *(const bf16x8*)&sBf[swzB((dc * 8 + ct) * 64 + lane) * 8];
      an[c] = __builtin_amdgcn_mfma_f32_16x16x32_bf16(fx2.h, wf, an[c], 0, 0, 0);
      s1[c] = __builtin_amdgcn_mfma_f32_16x16x32_bf16(faa.h, wf, s1[c], 0, 0, 0);
      s2[c] = __builtin_amdgcn_mfma_f32_16x16x32_bf16(fvv.h, wf, s2[c], 0, 0, 0);
    }
  }

  // ---- epilogue ----
#pragma unroll
  for (int c = 0; c < 4; ++c)
#pragma unroll
    for (int r = 0; r < 4; ++r) {
      float t = fmaxf(s1[c][r] * s2[c][r], 1e-16f);
      O[(size_t)(rowg * 16 + quad * 4 + r) * D + (colg * 4 + c) * 16 + ln] =
          an[c][r] * __builtin_amdgcn_rsqf(t);
    }
}

extern "C" void kernel_launch(void* const* d_in, const int* in_sizes, int n_in,
                              void* d_out, int out_size, void* d_ws, size_t ws_size,
                              hipStream_t stream) {
  const float* feats = (const float*)d_in[0];
  const float* w = (const float*)d_in[1];
  float* out = (float*)d_out;
  const int L = (in_sizes[0] / D) / GRAPHS;  // 2048

  const size_t partSlice = (size_t)GRAPHS * D * D * sizeof(unsigned short);  // 2 MiB
  const size_t gramB = partSlice;                                            // 2 MiB
  const size_t w2B = (size_t)D * D * sizeof(unsigned short);                 // 32 KiB
  int KS = 16;
  while (KS > 1 && (size_t)KS * partSlice + gramB + w2B > ws_size) KS >>= 1;

  unsigned short* partialBuf = (unsigned short*)d_ws;
  unsigned short* gramBuf = partialBuf + (size_t)KS * GRAPHS * D * D;
  unsigned short* w2Buf = gramBuf + (size_t)GRAPHS * D * D;

  hipLaunchKernelGGL(gram_partial_kernel, dim3(GRAPHS * KS), dim3(256), 0,
                     stream, feats, partialBuf, L, KS);
  hipLaunchKernelGGL(reduce_w2_kernel, dim3(520), dim3(256), 0, stream,
                     partialBuf, gramBuf, w, w2Buf, KS);
  hipLaunchKernelGGL(fused_kernel4, dim3(GRAPHS * (L >> 6)), dim3(512), 0,
                     stream, feats, gramBuf, w2Buf, out, L);
}